// Round 10
// baseline (1418.811 us; speedup 1.0000x reference)
//
#include <hip/hip_runtime.h>

typedef unsigned short u16;
using bf8   = __attribute__((ext_vector_type(8))) short;  // 8 bf16 (4 VGPRs)
using bf4   = __attribute__((ext_vector_type(4))) short;  // 4 bf16
using f32x4 = __attribute__((ext_vector_type(4))) float;

#define B_ 256
#define T_ 512
#define D_ 64
#define H_ 256
#define Tc_ 64
#define NC_ (T_ / Tc_)
#define GEMMB_ 191   // gemm blocks; 191*16 = 3056 waves >= 28 units * 109 j-slots

#define MFMA(a, b, c) __builtin_amdgcn_mfma_f32_16x16x32_bf16(a, b, c, 0, 0, 0)

static __device__ inline u16 f2b(float f) {
    unsigned int u = __float_as_uint(f);
    unsigned int r = (u + 0x7fffu + ((u >> 16) & 1u)) >> 16;
    return (u16)r;
}
static __device__ inline float b2f(u16 v) {
    return __uint_as_float((unsigned)v << 16);
}
static __device__ inline float fast_tanh(float x) {
    float e = __expf(2.f * x);
    return 1.f - 2.f / (e + 1.f);
}
static __device__ inline float fast_sigmoid(float x) {
    return 1.f / (1.f + __expf(-x));
}
// Raw barrier: waits LDS ops only, leaves global loads/stores in flight.
static __device__ inline void lds_barrier() {
    asm volatile("s_waitcnt lgkmcnt(0)" ::: "memory");
    __builtin_amdgcn_s_barrier();
    asm volatile("" ::: "memory");
}

// ---------------------------------------------------------------------------
// k_conv: f32 -> bf16 weight conversion pre-pass.
// ---------------------------------------------------------------------------
__global__ __launch_bounds__(256) void k_conv(
    const float* __restrict__ W1w, const float* __restrict__ U1w,
    const float* __restrict__ W2w, const float* __restrict__ U2w,
    const float* __restrict__ o1w, const float* __restrict__ o2w,
    const float* __restrict__ gw,
    u16* W1bf, u16* U1bf, u16* W2bf, u16* U2bf,
    u16* o1bf, u16* o2bf, u16* gbf)
{
    const int a = blockIdx.y;
    const float* src; u16* dst; int n;
    switch (a) {
        case 0: src = W1w; dst = W1bf; n = 16384;  break;
        case 1: src = U1w; dst = U1bf; n = 65536;  break;
        case 2: src = W2w; dst = W2bf; n = 65536;  break;
        case 3: src = U2w; dst = U2bf; n = 65536;  break;
        case 4: src = o1w; dst = o1bf; n = 16384;  break;
        case 5: src = o2w; dst = o2bf; n = 16384;  break;
        default: src = gw; dst = gbf;  n = 131072; break;
    }
    const int i = (blockIdx.x * 256 + threadIdx.x) * 4;
    if (i < n) {
        f32x4 v = *(const f32x4*)(src + i);
        bf4 o;
        o[0] = (short)f2b(v[0]); o[1] = (short)f2b(v[1]);
        o[2] = (short)f2b(v[2]); o[3] = (short)f2b(v[3]);
        *(bf4*)(dst + i) = o;
    }
}

// ---------------------------------------------------------------------------
// h1 role: blocks 0-15, 16 waves, ONE n-chain each (u1f[8]=32 regs resident;
// total ~70 regs -> fits the immovable 128 budget, zero restream).
// h1(t) = tanh(U1 @ h1(t-1) + X1c(t));  X1c precomputed by gemm role.
// ---------------------------------------------------------------------------
__device__ void h1_role(
    const u16* __restrict__ U1, const u16* __restrict__ X1c,
    u16* __restrict__ H1, u16* __restrict__ h1state, int c,
    u16 (*buf)[16][H_ + 8])
{
    const int g = blockIdx.x;
    const int tid = threadIdx.x;
    const int w = tid >> 6, lane = tid & 63;
    const int col = lane & 15, quad = lane >> 4;
    const int n = w * 16 + col;

    bf8 u1f[8];
#pragma unroll
    for (int kt = 0; kt < 8; ++kt)
        u1f[kt] = *(const bf8*)(U1 + (size_t)n * H_ + kt * 32 + quad * 8);

    if (c == 0) {
        for (int idx = tid; idx < 16 * (H_ + 8); idx += 1024)
            ((u16*)buf[0])[idx] = 0;
    } else {
        const int m = tid >> 6, hb = (tid & 63) * 4;
        *(bf4*)&buf[0][m][hb] =
            *(const bf4*)(h1state + (size_t)(g * 16 + m) * H_ + hb);
    }
    __syncthreads();

    bf4 x1r = *(const bf4*)(X1c + ((((size_t)g * Tc_ + 0) * 16 + w) * 64 + lane) * 4);

    int p = 0;
    for (int tt = 0; tt < Tc_; ++tt) {
        const int ttn = (tt + 1 < Tc_) ? tt + 1 : tt;
        bf4 x1n = *(const bf4*)(X1c +
            ((((size_t)g * Tc_ + ttn) * 16 + w) * 64 + lane) * 4);

        f32x4 acc;
#pragma unroll
        for (int r = 0; r < 4; ++r) acc[r] = b2f((u16)x1r[r]);
#pragma unroll
        for (int kt = 0; kt < 8; ++kt) {
            bf8 hf = *(const bf8*)&buf[p][col][kt * 32 + quad * 8];
            acc = MFMA(hf, u1f[kt], acc);
        }
#pragma unroll
        for (int r = 0; r < 4; ++r)
            buf[p ^ 1][quad * 4 + r][n] = f2b(fast_tanh(acc[r]));
        lds_barrier();
        {
            const int m = tid >> 6, hb = (tid & 63) * 4;
            bf4 v0 = *(const bf4*)&buf[p ^ 1][m][hb];
            *(bf4*)(H1 + ((size_t)tt * 256 + g * 16 + m) * H_ + hb) = v0;
        }
        x1r = x1n;
        p ^= 1;
    }
    {
        const int m = tid >> 6, hb = (tid & 63) * 4;
        *(bf4*)(h1state + (size_t)(g * 16 + m) * H_ + hb) =
            *(const bf4*)&buf[p][m][hb];
    }
}

// ---------------------------------------------------------------------------
// h2 role: blocks 16-31, 16 waves split into two teams so each weight matrix
// has a PERMANENT register home (64 regs/wave, fits the 128 budget):
//   U-team (waves 0-7):  U2 resident; owns h2 state; computes preact+blend.
//   G-team (waves 8-15): G2 resident; owns gate; u passes via LDS ubuf.
// Per step: phase A (U blends h2n(t) with u(t-1), writes h2(t) tile);
// barrier; phase B (G gate-GEMM on h2(t) -> u(t) || U next preact h2n(t+1),
// H2 store); barrier. The two 16-MFMA sections run CONCURRENTLY.
// ---------------------------------------------------------------------------
__device__ void h2_role(
    const u16* __restrict__ U2, const u16* __restrict__ gw,
    const float* __restrict__ W2c, const float* __restrict__ G1c,
    u16* __restrict__ H2, float* __restrict__ h2state,
    float* __restrict__ ustate, int ch,
    u16 (*buf)[16][H_ + 8], float (*ubuf)[H_ + 1])
{
    const int g = blockIdx.x - 16;
    const int tid = threadIdx.x;
    const int wv = tid >> 6, lane = tid & 63;
    const int col = lane & 15, quad = lane >> 4;
    const bool ut = (wv < 8);
    const int w = ut ? wv : wv - 8;
    const int n0 = (w * 2) * 16 + col;
    const int n1 = (w * 2 + 1) * 16 + col;

    bf8 wf[2][8];   // U-team: U2 rows; G-team: G2 rows (second half of g_w)
#pragma unroll
    for (int kt = 0; kt < 8; ++kt) {
        if (ut) {
            wf[0][kt] = *(const bf8*)(U2 + (size_t)n0 * H_ + kt * 32 + quad * 8);
            wf[1][kt] = *(const bf8*)(U2 + (size_t)n1 * H_ + kt * 32 + quad * 8);
        } else {
            wf[0][kt] = *(const bf8*)(gw + (size_t)n0 * (2 * H_) + H_ + kt * 32 + quad * 8);
            wf[1][kt] = *(const bf8*)(gw + (size_t)n1 * (2 * H_) + H_ + kt * 32 + quad * 8);
        }
    }

    f32x4 h2p[2], up[2];
    if (ut) {
        if (ch == 0) {
#pragma unroll
            for (int i = 0; i < 2; ++i) {
                h2p[i][0]=0.f; h2p[i][1]=0.f; h2p[i][2]=0.f; h2p[i][3]=0.f;
            }
        } else {
#pragma unroll
            for (int i = 0; i < 2; ++i)
                h2p[i] = *(const f32x4*)(h2state +
                    (((size_t)g * 16 + (w * 2 + i)) * 64 + lane) * 4);
        }
#pragma unroll
        for (int i = 0; i < 2; ++i) {
            const int nn = (w * 2 + i) * 16 + col;
#pragma unroll
            for (int r = 0; r < 4; ++r) buf[0][quad * 4 + r][nn] = f2b(h2p[i][r]);
        }
    } else {
        if (ch == 0) {
#pragma unroll
            for (int i = 0; i < 2; ++i) {
                up[i][0]=1.f; up[i][1]=1.f; up[i][2]=1.f; up[i][3]=1.f;
            }
        } else {
#pragma unroll
            for (int i = 0; i < 2; ++i)
                up[i] = *(const f32x4*)(ustate +
                    (((size_t)g * 16 + (w * 2 + i)) * 64 + lane) * 4);
        }
#pragma unroll
        for (int i = 0; i < 2; ++i) {
            const int nn = (w * 2 + i) * 16 + col;
#pragma unroll
            for (int r = 0; r < 4; ++r) ubuf[quad * 4 + r][nn] = up[i][r];
        }
    }
    __syncthreads();

    f32x4 h2n[2], g1cc[2];
    if (ut) {
        // prologue: h2n(0) = tanh(U2 @ h2(init) + W2c(0))
        f32x4 w2c0[2];
#pragma unroll
        for (int i = 0; i < 2; ++i)
            w2c0[i] = *(const f32x4*)(W2c +
                ((((size_t)g * Tc_ + 0) * 16 + (w * 2 + i)) * 64 + lane) * 4);
        f32x4 a0, a1;
        a0[0]=0.f; a0[1]=0.f; a0[2]=0.f; a0[3]=0.f; a1 = a0;
#pragma unroll
        for (int kt = 0; kt < 8; ++kt) {
            bf8 hf = *(const bf8*)&buf[0][col][kt * 32 + quad * 8];
            a0 = MFMA(hf, wf[0][kt], a0);
            a1 = MFMA(hf, wf[1][kt], a1);
        }
#pragma unroll
        for (int r = 0; r < 4; ++r) {
            h2n[0][r] = fast_tanh(a0[r] + w2c0[0][r]);
            h2n[1][r] = fast_tanh(a1[r] + w2c0[1][r]);
        }
    } else {
#pragma unroll
        for (int i = 0; i < 2; ++i)
            g1cc[i] = *(const f32x4*)(G1c +
                ((((size_t)g * Tc_ + 0) * 16 + (w * 2 + i)) * 64 + lane) * 4);
    }

    for (int tt = 0; tt < Tc_; ++tt) {
        const int pn = (tt + 1) & 1;
        if (ut) {
            // phase A: blend with u(t-1) from ubuf; write h2(t) tile
#pragma unroll
            for (int i = 0; i < 2; ++i) {
                const int nn = (w * 2 + i) * 16 + col;
#pragma unroll
                for (int r = 0; r < 4; ++r) {
                    float u = ubuf[quad * 4 + r][nn];
                    h2p[i][r] = u * h2n[i][r] + (1.f - u) * h2p[i][r];
                }
#pragma unroll
                for (int r = 0; r < 4; ++r)
                    buf[pn][quad * 4 + r][nn] = f2b(h2p[i][r]);
            }
        }
        lds_barrier();
        if (ut) {
            // store H2(t); compute h2n(t+1) from h2(t)
            {
                const int m = tid >> 5, hb = (tid & 31) * 8;
                bf8 v0 = *(const bf8*)&buf[pn][m][hb];
                *(bf8*)(H2 + ((size_t)tt * 256 + g * 16 + m) * H_ + hb) = v0;
            }
            if (tt + 1 < Tc_) {
                f32x4 w2n[2];
#pragma unroll
                for (int i = 0; i < 2; ++i)
                    w2n[i] = *(const f32x4*)(W2c +
                        ((((size_t)g * Tc_ + (tt + 1)) * 16 + (w * 2 + i)) * 64 + lane) * 4);
                f32x4 a0, a1;
                a0[0]=0.f; a0[1]=0.f; a0[2]=0.f; a0[3]=0.f; a1 = a0;
#pragma unroll
                for (int kt = 0; kt < 8; ++kt) {
                    bf8 hf = *(const bf8*)&buf[pn][col][kt * 32 + quad * 8];
                    a0 = MFMA(hf, wf[0][kt], a0);
                    a1 = MFMA(hf, wf[1][kt], a1);
                }
#pragma unroll
                for (int r = 0; r < 4; ++r) {
                    h2n[0][r] = fast_tanh(a0[r] + w2n[0][r]);
                    h2n[1][r] = fast_tanh(a1[r] + w2n[1][r]);
                }
            }
        } else {
            // phase B: gate GEMM on h2(t) -> u(t) -> ubuf
            f32x4 a0 = g1cc[0], a1 = g1cc[1];
#pragma unroll
            for (int kt = 0; kt < 8; ++kt) {
                bf8 hf = *(const bf8*)&buf[pn][col][kt * 32 + quad * 8];
                a0 = MFMA(hf, wf[0][kt], a0);
                a1 = MFMA(hf, wf[1][kt], a1);
            }
#pragma unroll
            for (int r = 0; r < 4; ++r) {
                up[0][r] = fast_sigmoid(a0[r]);
                up[1][r] = fast_sigmoid(a1[r]);
            }
#pragma unroll
            for (int i = 0; i < 2; ++i) {
                const int nn = (w * 2 + i) * 16 + col;
#pragma unroll
                for (int r = 0; r < 4; ++r) ubuf[quad * 4 + r][nn] = up[i][r];
            }
            if (tt + 1 < Tc_) {
#pragma unroll
                for (int i = 0; i < 2; ++i)
                    g1cc[i] = *(const f32x4*)(G1c +
                        ((((size_t)g * Tc_ + (tt + 1)) * 16 + (w * 2 + i)) * 64 + lane) * 4);
            }
        }
        lds_barrier();
    }
    if (ut) {
#pragma unroll
        for (int i = 0; i < 2; ++i)
            *(f32x4*)(h2state + (((size_t)g * 16 + (w * 2 + i)) * 64 + lane) * 4) = h2p[i];
    } else {
#pragma unroll
        for (int i = 0; i < 2; ++i)
            *(f32x4*)(ustate + (((size_t)g * 16 + (w * 2 + i)) * 64 + lane) * 4) = up[i];
    }
}

// ---------------------------------------------------------------------------
// k_pipe (1024-thread blocks): lag pipeline across dispatches, c = -1..NC_+2:
//   blocks 0-15 : h1 of chunk c              (0 <= c < NC_)
//   blocks 16-31: h2 of chunk c-2            (2 <= c <= NC_+1)
//   blocks 32+  : 28 gemm units x 109 j-slots, 2 n-tiles per wave (B-resident):
//     unit 0-7  : W2c  (chunk c-1, 1<=c<=NC_)
//     unit 8-15 : G1c  (chunk c-1)
//     unit 16-17: O1c  (chunk c-1)
//     unit 18-19: out  (chunk c-3, 3<=c<=NC_+2)
//     unit 20-27: X1c  (chunk c+1, c<=NC_-2)  [A = x (f32), K=64]
// LDS pad -> >80KB/WG -> 1 WG/CU -> natural RA budget 128 VGPR; every role's
// working set is designed to fit it (no restream anywhere).
// ---------------------------------------------------------------------------
__global__ __launch_bounds__(1024) void k_pipe(
    const float* __restrict__ x, const u16* __restrict__ W1,
    const u16* __restrict__ U1,
    const float* __restrict__ W1b, const float* __restrict__ U1b,
    const u16* __restrict__ X1cr, u16* __restrict__ X1cw,
    u16* __restrict__ H1w, u16* __restrict__ h1state,
    const u16* __restrict__ U2, const u16* __restrict__ gwgt,
    const float* __restrict__ W2cr_, const float* __restrict__ G1cr_,
    u16* __restrict__ H2w, float* __restrict__ h2state,
    float* __restrict__ ustate,
    const u16* __restrict__ H1r, const u16* __restrict__ W2,
    const u16* __restrict__ o1w, const u16* __restrict__ o2w,
    const float* __restrict__ W2b, const float* __restrict__ U2b,
    const float* __restrict__ gbias, const float* __restrict__ o1b,
    const float* __restrict__ o2b,
    float* __restrict__ W2cw, float* __restrict__ G1cw, float* __restrict__ O1cw,
    const u16* __restrict__ H2r, const float* __restrict__ O1r,
    float* __restrict__ out, int c)
{
    __shared__ __align__(16) u16 buf[2][16][H_ + 8];
    __shared__ __align__(16) float ubuf[16][H_ + 1];
    __shared__ u16 occpad[24576];   // pad total LDS > 80KB -> 1 WG/CU
    if (c < -100) {                 // never true (c >= -1); keeps occpad live
        ((volatile u16*)occpad)[threadIdx.x] = (u16)threadIdx.x;
        return;
    }
    if (blockIdx.x < 16) {
        if (c >= 0 && c < NC_)
            h1_role(U1, X1cr, H1w, h1state, c, buf);
    } else if (blockIdx.x < 32) {
        if (c >= 2 && c <= NC_ + 1)
            h2_role(U2, gwgt, W2cr_, G1cr_, H2w, h2state, ustate, c - 2, buf, ubuf);
    } else {
        const int gbk = blockIdx.x - 32;
        const int tid = threadIdx.x;
        const int w = tid >> 6, lane = tid & 63;
        const int col = lane & 15, quad = lane >> 4;
        const int Wv = gbk * 16 + w;
        const int unit = Wv % 28;
        const int j = Wv / 28;
        if (j >= 109) return;
        bool actv;
        if (unit < 18)      actv = (c >= 1 && c <= NC_);
        else if (unit < 20) actv = (c >= 3 && c <= NC_ + 2);
        else                actv = (c <= NC_ - 2);
        if (!actv) return;

        if (unit >= 20) {
            // X1 path: X1c(chunk c+1) = x @ W1^T + (W1b + U1b), K = 64
            const int u2i = unit - 20;
            bf8 bfx[2][2];
            float bias[2];
#pragma unroll
            for (int i = 0; i < 2; ++i) {
                const int n3 = (u2i * 2 + i) * 16 + col;
                bias[i] = W1b[n3] + U1b[n3];
#pragma unroll
                for (int kt = 0; kt < 2; ++kt)
                    bfx[i][kt] = *(const bf8*)(W1 + (size_t)n3 * D_ + kt * 32 + quad * 8);
            }
            const int tg0 = (c + 1) * Tc_;
            for (int mt = j; mt < 1024; mt += 109) {
                const int mrow = mt * 16;
                const int tt = mrow >> 8, gg = (mrow & 255) >> 4;
                const int b = gg * 16 + col;
                const float* xp = x + ((size_t)b * T_ + tg0 + tt) * D_ + quad * 8;
                bf8 xaf[2];
#pragma unroll
                for (int kt = 0; kt < 2; ++kt) {
                    f32x4 a0 = *(const f32x4*)(xp + kt * 32);
                    f32x4 a1 = *(const f32x4*)(xp + kt * 32 + 4);
                    bf8 v;
#pragma unroll
                    for (int jj = 0; jj < 4; ++jj) {
                        v[jj]     = (short)f2b(a0[jj]);
                        v[jj + 4] = (short)f2b(a1[jj]);
                    }
                    xaf[kt] = v;
                }
                f32x4 acc[2];
#pragma unroll
                for (int i = 0; i < 2; ++i) {
                    acc[i][0] = bias[i]; acc[i][1] = bias[i];
                    acc[i][2] = bias[i]; acc[i][3] = bias[i];
                }
#pragma unroll
                for (int kt = 0; kt < 2; ++kt) {
                    acc[0] = MFMA(xaf[kt], bfx[0][kt], acc[0]);
                    acc[1] = MFMA(xaf[kt], bfx[1][kt], acc[1]);
                }
#pragma unroll
                for (int i = 0; i < 2; ++i) {
                    const int nt3 = u2i * 2 + i;
                    bf4 o;
#pragma unroll
                    for (int r = 0; r < 4; ++r) o[r] = (short)f2b(acc[i][r]);
                    *(bf4*)(X1cw + ((((size_t)gg * Tc_ + tt) * 16 + nt3) * 64 + lane) * 4) = o;
                }
            }
        } else {
            // bf16 K=256 units
            bf8 bfv[2][8];
            float bias[2];
#pragma unroll
            for (int i = 0; i < 2; ++i) {
                const u16* bp; float bs;
                if (unit < 8)       { const int n = (unit * 2 + i) * 16 + col;
                                      bp = W2 + (size_t)n * H_;            bs = W2b[n] + U2b[n]; }
                else if (unit < 16) { const int n = ((unit - 8) * 2 + i) * 16 + col;
                                      bp = gwgt + (size_t)n * (2 * H_);    bs = gbias[n]; }
                else if (unit < 18) { const int n = ((unit - 16) * 2 + i) * 16 + col;
                                      bp = o1w + (size_t)n * H_;           bs = o1b[n] + o2b[n]; }
                else                { const int n = ((unit - 18) * 2 + i) * 16 + col;
                                      bp = o2w + (size_t)n * H_;           bs = 0.f; }
                bias[i] = bs;
#pragma unroll
                for (int kt = 0; kt < 8; ++kt)
                    bfv[i][kt] = *(const bf8*)(bp + kt * 32 + quad * 8);
            }
            const u16* Ar = (unit < 18) ? H1r : H2r;
            const int tb = (c - 3) * Tc_;

            for (int mt = j; mt < 1024; mt += 109) {
                const int mrow = mt * 16;
                f32x4 acc[2];
#pragma unroll
                for (int i = 0; i < 2; ++i) {
                    acc[i][0] = bias[i]; acc[i][1] = bias[i];
                    acc[i][2] = bias[i]; acc[i][3] = bias[i];
                }
#pragma unroll
                for (int kt = 0; kt < 8; ++kt) {
                    bf8 af = *(const bf8*)(Ar + (size_t)(mrow + col) * H_ + kt * 32 + quad * 8);
                    acc[0] = MFMA(af, bfv[0][kt], acc[0]);
                    acc[1] = MFMA(af, bfv[1][kt], acc[1]);
                }
                const int tt = mrow >> 8, gg = (mrow & 255) >> 4;
                if (unit < 8) {
#pragma unroll
                    for (int i = 0; i < 2; ++i) {
                        const int nt = unit * 2 + i;
                        *(f32x4*)(W2cw +
                            ((((size_t)gg * Tc_ + tt) * 16 + nt) * 64 + lane) * 4) = acc[i];
                    }
                } else if (unit < 16) {
#pragma unroll
                    for (int i = 0; i < 2; ++i) {
                        const int nt = (unit - 8) * 2 + i;
                        *(f32x4*)(G1cw +
                            ((((size_t)gg * Tc_ + tt) * 16 + nt) * 64 + lane) * 4) = acc[i];
                    }
                } else if (unit < 18) {
#pragma unroll
                    for (int i = 0; i < 2; ++i) {
                        const int ot = (unit - 16) * 2 + i;
                        *(f32x4*)(O1cw +
                            ((((size_t)gg * Tc_ + tt) * 4 + ot) * 64 + lane) * 4) = acc[i];
                    }
                } else {  // out = O1c (o1@h1 + biases) + h2 @ o2^T
#pragma unroll
                    for (int i = 0; i < 2; ++i) {
                        const int ot = (unit - 18) * 2 + i;
                        f32x4 o1v = *(const f32x4*)(O1r +
                            ((((size_t)gg * Tc_ + tt) * 4 + ot) * 64 + lane) * 4);
#pragma unroll
                        for (int r = 0; r < 4; ++r)
                            out[((size_t)(gg * 16 + quad * 4 + r) * T_ + (tb + tt)) * D_ +
                                ot * 16 + col] = acc[i][r] + o1v[r];
                    }
                }
            }
        }
    }
}

// ---------------------------------------------------------------------------
extern "C" void kernel_launch(void* const* d_in, const int* in_sizes, int n_in,
                              void* d_out, int out_size, void* d_ws, size_t ws_size,
                              hipStream_t stream)
{
    const float* x   = (const float*)d_in[0];
    const float* W1w = (const float*)d_in[1];
    const float* W1b = (const float*)d_in[2];
    const float* U1w = (const float*)d_in[3];
    const float* U1b = (const float*)d_in[4];
    const float* W2w = (const float*)d_in[5];
    const float* W2b = (const float*)d_in[6];
    const float* U2w = (const float*)d_in[7];
    const float* U2b = (const float*)d_in[8];
    const float* o1w = (const float*)d_in[9];
    const float* o1b = (const float*)d_in[10];
    const float* o2w = (const float*)d_in[11];
    const float* o2b = (const float*)d_in[12];
    const float* gw  = (const float*)d_in[13];
    const float* gb  = (const float*)d_in[14];
    float* out = (float*)d_out;
    (void)in_sizes; (void)n_in; (void)out_size; (void)ws_size;

    char* p = (char*)d_ws;
    u16* W1bf = (u16*)p; p += 16384 * 2;
    u16* U1bf = (u16*)p; p += 65536 * 2;
    u16* W2bf = (u16*)p; p += 65536 * 2;
    u16* U2bf = (u16*)p; p += 65536 * 2;
    u16* o1bf = (u16*)p; p += 16384 * 2;
    u16* o2bf = (u16*)p; p += 16384 * 2;
    u16* gbf  = (u16*)p; p += 131072 * 2;
    u16* H1[2]; u16* H2[2]; float* W2c[2]; float* G1c[2]; float* O1c[3];
    u16* X1c[2];
    for (int pa = 0; pa < 2; ++pa) {
        H1[pa]  = (u16*)p;   p += (size_t)Tc_ * 131072;   // Tc*256*256 bf16
        H2[pa]  = (u16*)p;   p += (size_t)Tc_ * 131072;   // Tc*256*256 bf16
        W2c[pa] = (float*)p; p += (size_t)Tc_ * 262144;   // Tc*256*256 f32
        G1c[pa] = (float*)p; p += (size_t)Tc_ * 262144;
        X1c[pa] = (u16*)p;   p += (size_t)Tc_ * 131072;   // Tc*256*256 bf16
    }
    for (int pa = 0; pa < 3; ++pa) {
        O1c[pa] = (float*)p; p += (size_t)Tc_ * 65536;    // Tc*256*64 f32
    }
    u16* h1s   = (u16*)p;  p += 131072;
    float* h2s = (float*)p; p += 262144;
    float* us  = (float*)p;

    k_conv<<<dim3(128, 7), 256, 0, stream>>>(W1w, U1w, W2w, U2w, o1w, o2w, gw,
                                             W1bf, U1bf, W2bf, U2bf, o1bf, o2bf, gbf);

    // dispatch c = { X1(c+1), h1(c), gemm(c-1), h2(c-2), out-gemm(c-3) }
    for (int c = -1; c <= NC_ + 2; ++c) {
        const int pw  = c & 1;                 // h1 writes H1[pw]; h2 writes H2[pw]
        const int pg  = (c + 1) & 1;           // gemm reads H1[pg]; out-gemm reads H2[pg]
        const int ph  = c & 1;                 // h2 reads W2c/G1c[ph]
        const int s_w = ((c - 1) % 3 + 3) % 3; // gemm writes O1c[s_w] (chunk c-1)
        const int s_r = ((c - 3) % 3 + 3) % 3; // out-gemm reads O1c[s_r] (chunk c-3)
        const int pxw = (c + 1) & 1;           // X1 writer: chunk c+1
        const int pxr = c & 1;                 // h1 reads X1 chunk c
        k_pipe<<<32 + GEMMB_, 1024, 0, stream>>>(
            x, W1bf, U1bf, W1b, U1b,
            X1c[pxr], X1c[pxw],
            H1[pw], h1s,
            U2bf, gbf, W2c[ph], G1c[ph], H2[pw], h2s, us,
            H1[pg], W2bf, o1bf, o2bf, W2b, U2b, gb, o1b, o2b,
            W2c[pg], G1c[pg], O1c[s_w],
            H2[pg], O1c[s_r], out, c);
    }
}